// Round 4
// baseline (127.529 us; speedup 1.0000x reference)
//
#include <hip/hip_runtime.h>
#include <hip/hip_bf16.h>
#include <cstddef>

#define T_DIM 2048
#define D_DIM 1024
#define GAMMA_F 0.96875f

typedef __attribute__((ext_vector_type(8))) short bf16x8;
typedef __attribute__((ext_vector_type(8))) ushort ushortx8;
typedef __attribute__((ext_vector_type(4))) float f32x4;

static __device__ inline ushort f2bs(float f) {
    __hip_bfloat16 h = __float2bfloat16(f);
    return *reinterpret_cast<ushort*>(&h);
}

// ---------------------------------------------------------------------------
// K0: wv_sum[i] = sum_d Wv[i][d]
// ---------------------------------------------------------------------------
__global__ __launch_bounds__(256) void k_wvsum(const float* __restrict__ Wv,
                                               float* __restrict__ wv_sum) {
    __shared__ float red[4];
    const int i = blockIdx.x;
    const int tid = threadIdx.x;
    const float* row = Wv + (size_t)i * D_DIM;
    float p = 0.f;
    for (int c = tid; c < D_DIM; c += 256) p += row[c];
    for (int o = 32; o; o >>= 1) p += __shfl_down(p, o);
    if ((tid & 63) == 0) red[tid >> 6] = p;
    __syncthreads();
    if (tid == 0) wv_sum[i] = red[0] + red[1] + red[2] + red[3];
}

// ---------------------------------------------------------------------------
// K1: per t: vsum[b] = x[b,t,:].wv_sum;  y[t,i] = sum_b x[b,t,i]*vsum[b]
// Emits bf16 ROW-MAJOR: yb [T,D], xb [B*T,D]. Vectorized loads/stores.
// ---------------------------------------------------------------------------
__global__ __launch_bounds__(256) void k_vsum_y(const float* __restrict__ x,
                                                const float* __restrict__ wv_sum,
                                                ushort* __restrict__ yb,
                                                ushort* __restrict__ xb) {
    __shared__ float xs[4][D_DIM];
    __shared__ float red[4][4];   // [wave][b]
    const int t = blockIdx.x;
    const int tid = threadIdx.x;
    const int lane = tid & 63, wv = tid >> 6;

    #pragma unroll
    for (int b = 0; b < 4; ++b) {
        const float4* xr = (const float4*)(x + ((size_t)b * T_DIM + t) * D_DIM);
        *(float4*)&xs[b][tid * 4] = xr[tid];
    }
    __syncthreads();

    #pragma unroll
    for (int b = 0; b < 4; ++b) {
        float p = 0.f;
        for (int c = tid; c < D_DIM; c += 256) p += xs[b][c] * wv_sum[c];
        for (int o = 32; o; o >>= 1) p += __shfl_down(p, o);
        if (lane == 0) red[wv][b] = p;
    }
    __syncthreads();

    float vs[4];
    #pragma unroll
    for (int b = 0; b < 4; ++b)
        vs[b] = red[0][b] + red[1][b] + red[2][b] + red[3][b];

    if (tid < 128) {                       // y row t: 128 groups of 8
        const int i0 = tid * 8;
        ushortx8 yv;
        #pragma unroll
        for (int j = 0; j < 8; ++j) {
            float a = 0.f;
            #pragma unroll
            for (int b = 0; b < 4; ++b) a += xs[b][i0 + j] * vs[b];
            yv[j] = f2bs(a);
        }
        *(ushortx8*)(yb + (size_t)t * D_DIM + i0) = yv;
    }
    for (int g = tid; g < 512; g += 256) { // xb rows b*T+t
        const int b = g >> 7, i0 = (g & 127) * 8;
        ushortx8 xv;
        #pragma unroll
        for (int j = 0; j < 8; ++j) xv[j] = f2bs(xs[b][i0 + j]);
        *(ushortx8*)(xb + ((size_t)b * T_DIM + t) * D_DIM + i0) = xv;
    }
}

// ---------------------------------------------------------------------------
// K2: W [K=1024][N=1024] fp32 -> WT frag-packed bf16 as B-operand [N,K]:
// elem (n,k) -> ((n>>4)*32 + (k>>5))*512 + ((k>>3)&3)*128 + (n&15)*8 + (k&7)
// so a wave's B-fragment (16 cols x 32 k) is one contiguous 1KB chunk.
// ---------------------------------------------------------------------------
__global__ __launch_bounds__(256) void k_cvtWT(const float* __restrict__ W,
                                               ushort* __restrict__ WT) {
    __shared__ float tile[32][33];          // [k][n]
    const int tid = threadIdx.x;
    const int tx = tid & 31, ty = tid >> 5; // 32 x 8
    const int kb = blockIdx.x * 32, nb = blockIdx.y * 32;
    #pragma unroll
    for (int r = 0; r < 4; ++r)
        tile[ty + 8 * r][tx] = W[(size_t)(kb + ty + 8 * r) * 1024 + nb + tx];
    __syncthreads();
    if (tid < 128) {
        const int n = tid & 31, kg = tid >> 5;   // kg 0..3
        const int gn = nb + n, k0 = kb + kg * 8;
        ushortx8 v;
        #pragma unroll
        for (int j = 0; j < 8; ++j) v[j] = f2bs(tile[kg * 8 + j][n]);
        const size_t addr = ((size_t)(gn >> 4) * 32 + (k0 >> 5)) * 512 +
                            (size_t)((k0 >> 3) & 3) * 128 + (gn & 15) * 8;
        *(ushortx8*)(WT + addr) = v;
    }
}

// ---------------------------------------------------------------------------
// K3: no-LDS MFMA GEMM  C[M,1024] = A[M,1024] @ B[1024,1024]
// A row-major bf16; B frag-packed (k_cvtWT). 4 waves (2x2); per wave
// MF x NF fragments of 16x16 (block tile 32*MF x 32*NF). K=1024 fixed.
// Fragments stream straight global->VGPR (A: 16x64B segs, L1-shared;
// B: contiguous 1KB, L2-resident). Register ping-pong, no barriers.
// EPI=1 fuses out[r,d] = acc * S[2d + (t>>10)][t&1023], t = r & 2047.
// ---------------------------------------------------------------------------
template <int MF, int NF, int EPI>
__global__ __launch_bounds__(256) void k_gemm_frag(const ushort* __restrict__ A,
                                                   const ushort* __restrict__ B,
                                                   float* __restrict__ C,
                                                   const float* __restrict__ S) {
    const int tid = threadIdx.x;
    const int lane = tid & 63, wid = tid >> 6;
    const int wr = wid >> 1, wc = wid & 1;
    const int m0  = (blockIdx.x * 2 * MF + wr * MF) * 16;  // first row
    const int nf0 = blockIdx.y * 2 * NF + wc * NF;         // first n-frag

    // A: lane reads row m0+i*16+(lane&15), k = kt*32 + (lane>>4)*8
    const ushort* Ap = A + (size_t)(m0 + (lane & 15)) * 1024 + ((lane >> 4) * 8);
    // B: frag (nf, kt) at (nf*32+kt)*512 + lane*8
    const ushort* Bp = B + (size_t)nf0 * 32 * 512 + lane * 8;

    f32x4 acc[MF][NF];
    #pragma unroll
    for (int i = 0; i < MF; ++i)
        #pragma unroll
        for (int j = 0; j < NF; ++j) acc[i][j] = f32x4{0.f, 0.f, 0.f, 0.f};

    bf16x8 aP[MF], bP[NF], aQ[MF], bQ[NF];
    #pragma unroll
    for (int i = 0; i < MF; ++i)
        aP[i] = *(const bf16x8*)(Ap + (size_t)i * 16 * 1024);
    #pragma unroll
    for (int j = 0; j < NF; ++j)
        bP[j] = *(const bf16x8*)(Bp + (size_t)j * 32 * 512);

    #pragma unroll 1
    for (int kt = 0; kt < 32; kt += 2) {
        #pragma unroll
        for (int i = 0; i < MF; ++i)
            aQ[i] = *(const bf16x8*)(Ap + (size_t)i * 16 * 1024 + (kt + 1) * 32);
        #pragma unroll
        for (int j = 0; j < NF; ++j)
            bQ[j] = *(const bf16x8*)(Bp + ((size_t)j * 32 + kt + 1) * 512);
        #pragma unroll
        for (int i = 0; i < MF; ++i)
            #pragma unroll
            for (int j = 0; j < NF; ++j)
                acc[i][j] = __builtin_amdgcn_mfma_f32_16x16x32_bf16(
                    aP[i], bP[j], acc[i][j], 0, 0, 0);
        const int kn = (kt + 2) & 31;   // wraps to 0 on last iter (dead reload)
        #pragma unroll
        for (int i = 0; i < MF; ++i)
            aP[i] = *(const bf16x8*)(Ap + (size_t)i * 16 * 1024 + kn * 32);
        #pragma unroll
        for (int j = 0; j < NF; ++j)
            bP[j] = *(const bf16x8*)(Bp + ((size_t)j * 32 + kn) * 512);
        #pragma unroll
        for (int i = 0; i < MF; ++i)
            #pragma unroll
            for (int j = 0; j < NF; ++j)
                acc[i][j] = __builtin_amdgcn_mfma_f32_16x16x32_bf16(
                    aQ[i], bQ[j], acc[i][j], 0, 0, 0);
    }

    #pragma unroll
    for (int i = 0; i < MF; ++i) {
        #pragma unroll
        for (int j = 0; j < NF; ++j) {
            const int col = (nf0 + j) * 16 + (lane & 15);
            #pragma unroll
            for (int q = 0; q < 4; ++q) {
                const int row = m0 + i * 16 + (lane >> 4) * 4 + q;
                float v = acc[i][j][q];
                if (EPI) {
                    const int t = row & (T_DIM - 1);
                    v *= S[(size_t)(2 * col + (t >> 10)) * D_DIM + (t & 1023)];
                }
                C[(size_t)row * D_DIM + col] = v;
            }
        }
    }
}

// ---------------------------------------------------------------------------
// Parallel scan over t: S[t] = g*S[t-1] + m[t], m[0]:=0, then S[0]=S[1].
// ---------------------------------------------------------------------------
#define SC_L 32
#define SC_NC 64

__global__ __launch_bounds__(256) void k_scan1(const float* __restrict__ m,
                                               float* __restrict__ tot) {
    const int col = blockIdx.x * 64 + (threadIdx.x & 63);
    const int ch  = blockIdx.y * 4 + (threadIdx.x >> 6);
    const int t0 = ch * SC_L;
    float r = 0.f;
    #pragma unroll 4
    for (int k = 0; k < SC_L; ++k) {
        const int t = t0 + k;
        const float a = (t == 0) ? 0.f : m[(size_t)t * D_DIM + col];
        r = GAMMA_F * r + a;
    }
    tot[(size_t)ch * D_DIM + col] = r;
}

__global__ __launch_bounds__(256) void k_scan2(float* __restrict__ m,
                                               const float* __restrict__ tot) {
    const int col = blockIdx.x * 64 + (threadIdx.x & 63);
    const int ch  = blockIdx.y * 4 + (threadIdx.x >> 6);
    const int t0 = ch * SC_L;

    float gL = 1.f;
    #pragma unroll
    for (int i = 0; i < SC_L; ++i) gL *= GAMMA_F;

    float carry = 0.f, f = 1.f;    // carry = sum_{j<ch} (g^L)^(ch-1-j) tot[j]
    for (int j = ch - 1; j >= 0; --j) {
        carry += f * tot[(size_t)j * D_DIM + col];
        f *= gL;
    }

    float r = carry, s1 = 0.f;
    #pragma unroll 4
    for (int k = 0; k < SC_L; ++k) {
        const int t = t0 + k;
        const float a = (t == 0) ? 0.f : m[(size_t)t * D_DIM + col];
        r = GAMMA_F * r + a;
        m[(size_t)t * D_DIM + col] = r;
        if (t == 1) s1 = r;
    }
    if (ch == 0) m[col] = s1;      // S[0] = S[1]
}

// ---------------------------------------------------------------------------
extern "C" void kernel_launch(void* const* d_in, const int* in_sizes, int n_in,
                              void* d_out, int out_size, void* d_ws, size_t ws_size,
                              hipStream_t stream) {
    const float* x  = (const float*)d_in[0];   // [4,2048,1024]
    const float* Wq = (const float*)d_in[1];
    const float* Wk = (const float*)d_in[2];
    const float* Wv = (const float*)d_in[3];
    float* out = (float*)d_out;                // [4,2048,1024] fp32
    char* ws = (char*)d_ws;

    // ws layout, 30 MB total:
    ushort* xb  = (ushort*)(ws);                    // 16 MB  [B*T,D] bf16 row-major
    float*  m   = (float*)(ws + (16u << 20));       //  8 MB  [T,D] fp32
    ushort* yb  = (ushort*)(ws + (24u << 20));      //  4 MB  [T,D] bf16 row-major
    ushort* WTk = (ushort*)(ws + (28u << 20));      //  2 MB  frag-packed
    float*  wv_sum = m;                             // m row 0: free until gemm<0>
    float*  tot = (float*)yb;                       // 256 KB, after gemm<0> reads yb
    ushort* WTq = (ushort*)(ws + (26u << 20));      //  2 MB, upper half of yb region

    k_wvsum<<<D_DIM, 256, 0, stream>>>(Wv, wv_sum);

    dim3 gW(32, 32);
    k_cvtWT<<<gW, 256, 0, stream>>>(Wk, WTk);

    k_vsum_y<<<T_DIM, 256, 0, stream>>>(x, wv_sum, yb, xb);

    // m = y @ Wk : block tile 128x64, grid (16,16) = 256 blocks (1/CU)
    dim3 gm(T_DIM / 128, D_DIM / 64);
    k_gemm_frag<4, 2, 0><<<gm, 256, 0, stream>>>(yb, WTk, m, nullptr);

    // yb region free now -> WTq (stream order guarantees gemm<0> finished)
    k_cvtWT<<<gW, 256, 0, stream>>>(Wq, WTq);

    dim3 gs(D_DIM / 64, SC_NC / 4);
    k_scan1<<<gs, 256, 0, stream>>>(m, tot);
    k_scan2<<<gs, 256, 0, stream>>>(m, tot);

    // out = (S-scramble) * (x @ Wq) : block tile 128x128, grid (64,8)
    dim3 gq((4 * T_DIM) / 128, D_DIM / 128);
    k_gemm_frag<4, 4, 1><<<gq, 256, 0, stream>>>(xb, WTq, out, m);
}

// Round 5
// 99.738 us; speedup vs baseline: 1.2786x; 1.2786x over previous
//
#include <hip/hip_runtime.h>
#include <hip/hip_bf16.h>
#include <cstddef>

#define T_DIM 2048
#define D_DIM 1024
#define GAMMA_F 0.96875f

typedef __attribute__((ext_vector_type(8))) short bf16x8;
typedef __attribute__((ext_vector_type(8))) ushort ushortx8;
typedef __attribute__((ext_vector_type(4))) float f32x4;

#define AS1 __attribute__((address_space(1)))
#define AS3 __attribute__((address_space(3)))

static __device__ inline ushort f2bs(float f) {
    __hip_bfloat16 h = __float2bfloat16(f);
    return *reinterpret_cast<ushort*>(&h);
}

// ---------------------------------------------------------------------------
// K0: wv_sum[i] = sum_d Wv[i][d]
// ---------------------------------------------------------------------------
__global__ __launch_bounds__(256) void k_wvsum(const float* __restrict__ Wv,
                                               float* __restrict__ wv_sum) {
    __shared__ float red[4];
    const int i = blockIdx.x;
    const int tid = threadIdx.x;
    const float* row = Wv + (size_t)i * D_DIM;
    float p = 0.f;
    for (int c = tid; c < D_DIM; c += 256) p += row[c];
    for (int o = 32; o; o >>= 1) p += __shfl_down(p, o);
    if ((tid & 63) == 0) red[tid >> 6] = p;
    __syncthreads();
    if (tid == 0) wv_sum[i] = red[0] + red[1] + red[2] + red[3];
}

// ---------------------------------------------------------------------------
// K1: per t: vsum[b] = x[b,t,:].wv_sum;  y[t,i] = sum_b x[b,t,i]*vsum[b]
// Emits bf16 ROW-MAJOR: yb [T,D], xb [B*T,D]. Vectorized loads/stores.
// ---------------------------------------------------------------------------
__global__ __launch_bounds__(256) void k_vsum_y(const float* __restrict__ x,
                                                const float* __restrict__ wv_sum,
                                                ushort* __restrict__ yb,
                                                ushort* __restrict__ xb) {
    __shared__ float xs[4][D_DIM];
    __shared__ float red[4][4];   // [wave][b]
    const int t = blockIdx.x;
    const int tid = threadIdx.x;
    const int lane = tid & 63, wv = tid >> 6;

    #pragma unroll
    for (int b = 0; b < 4; ++b) {
        const float4* xr = (const float4*)(x + ((size_t)b * T_DIM + t) * D_DIM);
        *(float4*)&xs[b][tid * 4] = xr[tid];
    }
    __syncthreads();

    #pragma unroll
    for (int b = 0; b < 4; ++b) {
        float p = 0.f;
        for (int c = tid; c < D_DIM; c += 256) p += xs[b][c] * wv_sum[c];
        for (int o = 32; o; o >>= 1) p += __shfl_down(p, o);
        if (lane == 0) red[wv][b] = p;
    }
    __syncthreads();

    float vs[4];
    #pragma unroll
    for (int b = 0; b < 4; ++b)
        vs[b] = red[0][b] + red[1][b] + red[2][b] + red[3][b];

    if (tid < 128) {                       // y row t: 128 groups of 8
        const int i0 = tid * 8;
        ushortx8 yv;
        #pragma unroll
        for (int j = 0; j < 8; ++j) {
            float a = 0.f;
            #pragma unroll
            for (int b = 0; b < 4; ++b) a += xs[b][i0 + j] * vs[b];
            yv[j] = f2bs(a);
        }
        *(ushortx8*)(yb + (size_t)t * D_DIM + i0) = yv;
    }
    for (int g = tid; g < 512; g += 256) { // xb rows b*T+t
        const int b = g >> 7, i0 = (g & 127) * 8;
        ushortx8 xv;
        #pragma unroll
        for (int j = 0; j < 8; ++j) xv[j] = f2bs(xs[b][i0 + j]);
        *(ushortx8*)(xb + ((size_t)b * T_DIM + t) * D_DIM + i0) = xv;
    }
}

// ---------------------------------------------------------------------------
// K2: W [K=1024][N=1024] fp32 -> BT [N][K] bf16 (row-major transpose)
// ---------------------------------------------------------------------------
__global__ __launch_bounds__(256) void k_cvtWT(const float* __restrict__ W,
                                               ushort* __restrict__ WT) {
    __shared__ float tile[32][33];          // [k][n]
    const int tx = threadIdx.x & 31, ty = threadIdx.x >> 5;  // 32 x 8
    const int kb = blockIdx.x * 32, nb = blockIdx.y * 32;
    #pragma unroll
    for (int r = 0; r < 4; ++r)
        tile[ty + 8 * r][tx] = W[(size_t)(kb + ty + 8 * r) * 1024 + nb + tx];
    __syncthreads();
    #pragma unroll
    for (int r = 0; r < 4; ++r)
        WT[(size_t)(nb + ty + 8 * r) * 1024 + kb + tx] =
            f2bs(tile[tx][ty + 8 * r]);
}

// ---------------------------------------------------------------------------
// K3: bf16 MFMA GEMM  C[M,1024] = A[M,1024] @ B[1024,1024]
// A [M,K] bf16 row-major; BT [N,K] bf16. Tile 128 x (NF*32), BK=64,
// 4 waves (2x2), per-wave 64 x (NF*16). LDS rows are 128B -> XOR-swizzle
// (grp ^= row&7, 16B granules) applied on BOTH sides: global source is
// inverse-swizzled (gload_lds dest stays linear, rule #21), ds_read uses
// the swizzled offset. 32 MFMA between barrier pairs (2x fewer barriers
// per FLOP than BK=32).
// EPI=1 fuses out[r,d] = acc * S[2d + (t>>10)][t&1023], t = r & 2047.
// ---------------------------------------------------------------------------
template <int NF, int EPI>
__global__ __launch_bounds__(256) void k_gemm(const ushort* __restrict__ A,
                                              const ushort* __restrict__ BT,
                                              float* __restrict__ C,
                                              const float* __restrict__ S) {
    constexpr int BN = NF * 32;            // block cols (64 or 128)
    __shared__ ushort As[128][64];         // 16 KB
    __shared__ ushort Bs[BN][64];          // 8/16 KB
    const int tid = threadIdx.x;
    const int lane = tid & 63, wid = tid >> 6;
    const int wr = wid >> 1, wc = wid & 1;
    const int rowBase = blockIdx.x * 128;
    const int colBase = blockIdx.y * BN;

    f32x4 acc[4][NF];
    #pragma unroll
    for (int i = 0; i < 4; ++i)
        #pragma unroll
        for (int j = 0; j < NF; ++j) acc[i][j] = f32x4{0.f, 0.f, 0.f, 0.f};

    for (int kb = 0; kb < 1024; kb += 64) {
        // ---- stage A (4 x 4KB issues) and B (BN/32 issues), swizzled source
        #pragma unroll
        for (int q = 0; q < 4; ++q) {
            const int s = q * 4096 + tid * 16;           // linear LDS byte
            const int r = s >> 7, grp = (s >> 4) & 7;
            const int gcol = kb + (((grp ^ (r & 7)) & 7) << 3);
            __builtin_amdgcn_global_load_lds(
                (const AS1 void*)(A + (size_t)(rowBase + r) * 1024 + gcol),
                (AS3 void*)((AS3 char*)&As[0][0] + s), 16, 0, 0);
        }
        #pragma unroll
        for (int q = 0; q < BN / 32; ++q) {
            const int s = q * 4096 + tid * 16;
            const int r = s >> 7, grp = (s >> 4) & 7;
            const int gcol = kb + (((grp ^ (r & 7)) & 7) << 3);
            __builtin_amdgcn_global_load_lds(
                (const AS1 void*)(BT + (size_t)(colBase + r) * 1024 + gcol),
                (AS3 void*)((AS3 char*)&Bs[0][0] + s), 16, 0, 0);
        }
        __syncthreads();

        // ---- fragments (swizzled ds_read) + 32 MFMA
        bf16x8 af[2][4], bfv[2][NF];
        #pragma unroll
        for (int ks = 0; ks < 2; ++ks) {
            const int kg = ks * 4 + (lane >> 4);
            #pragma unroll
            for (int mi = 0; mi < 4; ++mi) {
                const int r = wr * 64 + mi * 16 + (lane & 15);
                af[ks][mi] = *(const bf16x8*)((const char*)&As[0][0] +
                                              r * 128 + (((kg ^ (r & 7)) & 7) << 4));
            }
            #pragma unroll
            for (int ni = 0; ni < NF; ++ni) {
                const int r = wc * (NF * 16) + ni * 16 + (lane & 15);
                bfv[ks][ni] = *(const bf16x8*)((const char*)&Bs[0][0] +
                                               r * 128 + (((kg ^ (r & 7)) & 7) << 4));
            }
        }
        #pragma unroll
        for (int ks = 0; ks < 2; ++ks)
            #pragma unroll
            for (int mi = 0; mi < 4; ++mi)
                #pragma unroll
                for (int ni = 0; ni < NF; ++ni)
                    acc[mi][ni] = __builtin_amdgcn_mfma_f32_16x16x32_bf16(
                        af[ks][mi], bfv[ks][ni], acc[mi][ni], 0, 0, 0);
        __syncthreads();
    }

    #pragma unroll
    for (int mi = 0; mi < 4; ++mi) {
        #pragma unroll
        for (int ni = 0; ni < NF; ++ni) {
            const int col = colBase + wc * (NF * 16) + ni * 16 + (lane & 15);
            #pragma unroll
            for (int q = 0; q < 4; ++q) {
                const int row = rowBase + wr * 64 + mi * 16 + (lane >> 4) * 4 + q;
                float v = acc[mi][ni][q];
                if (EPI) {
                    const int t = row & (T_DIM - 1);
                    v *= S[(size_t)(2 * col + (t >> 10)) * D_DIM + (t & 1023)];
                }
                C[(size_t)row * D_DIM + col] = v;
            }
        }
    }
}

// ---------------------------------------------------------------------------
// Parallel scan over t: S[t] = g*S[t-1] + m[t], m[0]:=0, then S[0]=S[1].
// 64 chunks of 32 per column.
// ---------------------------------------------------------------------------
#define SC_L 32
#define SC_NC 64

__global__ __launch_bounds__(256) void k_scan1(const float* __restrict__ m,
                                               float* __restrict__ tot) {
    const int col = blockIdx.x * 64 + (threadIdx.x & 63);
    const int ch  = blockIdx.y * 4 + (threadIdx.x >> 6);
    const int t0 = ch * SC_L;
    float r = 0.f;
    #pragma unroll 4
    for (int k = 0; k < SC_L; ++k) {
        const int t = t0 + k;
        const float a = (t == 0) ? 0.f : m[(size_t)t * D_DIM + col];
        r = GAMMA_F * r + a;
    }
    tot[(size_t)ch * D_DIM + col] = r;
}

__global__ __launch_bounds__(256) void k_scan2(float* __restrict__ m,
                                               const float* __restrict__ tot) {
    const int col = blockIdx.x * 64 + (threadIdx.x & 63);
    const int ch  = blockIdx.y * 4 + (threadIdx.x >> 6);
    const int t0 = ch * SC_L;

    float gL = 1.f;
    #pragma unroll
    for (int i = 0; i < SC_L; ++i) gL *= GAMMA_F;

    float carry = 0.f, f = 1.f;    // carry = sum_{j<ch} (g^L)^(ch-1-j) tot[j]
    for (int j = ch - 1; j >= 0; --j) {
        carry += f * tot[(size_t)j * D_DIM + col];
        f *= gL;
    }

    float r = carry, s1 = 0.f;
    #pragma unroll 4
    for (int k = 0; k < SC_L; ++k) {
        const int t = t0 + k;
        const float a = (t == 0) ? 0.f : m[(size_t)t * D_DIM + col];
        r = GAMMA_F * r + a;
        m[(size_t)t * D_DIM + col] = r;
        if (t == 1) s1 = r;
    }
    if (ch == 0) m[col] = s1;      // S[0] = S[1]
}

// ---------------------------------------------------------------------------
extern "C" void kernel_launch(void* const* d_in, const int* in_sizes, int n_in,
                              void* d_out, int out_size, void* d_ws, size_t ws_size,
                              hipStream_t stream) {
    const float* x  = (const float*)d_in[0];   // [4,2048,1024]
    const float* Wq = (const float*)d_in[1];
    const float* Wk = (const float*)d_in[2];
    const float* Wv = (const float*)d_in[3];
    float* out = (float*)d_out;                // [4,2048,1024] fp32
    char* ws = (char*)d_ws;

    // ws layout, 30 MB total (proven available):
    ushort* xb  = (ushort*)(ws);                    // 16 MB  [B*T,D] bf16
    float*  m   = (float*)(ws + (16u << 20));       //  8 MB  [T,D] fp32
    ushort* yb  = (ushort*)(ws + (24u << 20));      //  4 MB  [T,D] bf16
    ushort* WT  = (ushort*)(ws + (28u << 20));      //  2 MB  BT (Wk then Wq)
    float*  wv_sum = m;                 // m row 0: free until gemm<0> writes it
    float*  tot = (float*)yb;           // yb consumed by gemm<0> before scans

    k_wvsum<<<D_DIM, 256, 0, stream>>>(Wv, wv_sum);
    k_vsum_y<<<T_DIM, 256, 0, stream>>>(x, wv_sum, (ushort*)yb, (ushort*)xb);

    dim3 gW(32, 32);
    k_cvtWT<<<gW, 256, 0, stream>>>(Wk, WT);

    // m = y @ Wk : tile 128x64, grid (16,16) = 256 blocks (1/CU)
    dim3 gm(T_DIM / 128, D_DIM / 64);
    k_gemm<2, 0><<<gm, 256, 0, stream>>>(yb, WT, m, nullptr);

    dim3 gs(D_DIM / 64, SC_NC / 4);
    k_scan1<<<gs, 256, 0, stream>>>(m, tot);
    k_scan2<<<gs, 256, 0, stream>>>(m, tot);

    k_cvtWT<<<gW, 256, 0, stream>>>(Wq, WT);   // reuse after gemm<0> done

    // out = (S-scramble) * (x @ Wq) : tile 128x128, grid (64,8) = 512 blocks
    dim3 gq((4 * T_DIM) / 128, D_DIM / 128);
    k_gemm<4, 1><<<gq, 256, 0, stream>>>(xb, WT, out, m);
}